// Round 7
// baseline (438.743 us; speedup 1.0000x reference)
//
#include <hip/hip_runtime.h>
#include <math.h>

// KGVAE: 2-layer RelGraphConv (bdd) + reparameterize, R7.
// Self-loop GEMV extracted into streaming GEMM kernels (weight column held in
// VGPRs, one coalesced row load + 64 readlane-FMA per node). Edge kernels keep
// R6 readlane/partial-product core minus self-loop; persistent grid-stride.
// ws: deg[N] | fil[N] | off[N+1] | h1[N*64] | h2b[N*128] | pkA[E] | pkB[E] | norm_s[E]

__device__ __forceinline__ int bcasti(int v, int l) {
    return __builtin_amdgcn_readlane(v, l);
}
__device__ __forceinline__ float bcastf(float v, int l) {
    return __int_as_float(__builtin_amdgcn_readlane(__float_as_int(v), l));
}

__global__ void hist(const int* __restrict__ dst, int* __restrict__ deg, int e) {
    int i = blockIdx.x * blockDim.x + threadIdx.x;
    if (i < e) atomicAdd(&deg[dst[i]], 1);
}

__global__ void scan_deg(const int* __restrict__ deg, int* __restrict__ off, int n) {
    __shared__ int part[1024];
    int t = threadIdx.x;
    int chunk = (n + 1023) / 1024;
    int lo = t * chunk, hi = lo + chunk;
    if (hi > n) hi = n;
    int s = 0;
    for (int i = lo; i < hi; ++i) s += deg[i];
    part[t] = s;
    __syncthreads();
    for (int d = 1; d < 1024; d <<= 1) {
        int v = (t >= d) ? part[t - d] : 0;
        __syncthreads();
        part[t] += v;
        __syncthreads();
    }
    int run = part[t] - s;
    for (int i = lo; i < hi; ++i) { off[i] = run; run += deg[i]; }
    if (t == 1023) off[n] = part[1023];
}

// packA = h_ids[src] | rel<<16 (layer1 gathers emb); packB = src | rel<<16 (layer2 gathers h1)
__global__ void scatter_pack(const int* __restrict__ src, const int* __restrict__ dst,
                             const int* __restrict__ rel, const float* __restrict__ norm,
                             const int* __restrict__ h_ids, const int* __restrict__ off,
                             int* __restrict__ fil, unsigned* __restrict__ packA,
                             unsigned* __restrict__ packB, float* __restrict__ norm_s, int e) {
    int i = blockIdx.x * blockDim.x + threadIdx.x;
    if (i >= e) return;
    int d = dst[i];
    int p = off[d] + atomicAdd(&fil[d], 1);
    unsigned rhi = (unsigned)rel[i] << 16;
    int s = src[i];
    packA[p] = (unsigned)h_ids[s] | rhi;
    packB[p] = (unsigned)s | rhi;
    norm_s[p] = norm[i];
}

// Streaming self-loop GEMM: out[n][col] = bias[col] + sum_k act(in[n][k]) * W[k][col]
// Wave holds W column `col` in 64 VGPRs; per node: 1 coalesced load + 64 readlane-FMA.
__global__ __launch_bounds__(256, 4) void
gemm_sl(const float* __restrict__ inbuf, const int* __restrict__ h_ids, int use_hids,
        int relu_in, const float* __restrict__ W, const float* __restrict__ bias,
        float* __restrict__ outbuf, int n_nodes, int OUT) {
    int tid = threadIdx.x;
    int w = tid >> 6, j = tid & 63;
    int col = blockIdx.y * 64 + j;
    float wreg[64];
#pragma unroll
    for (int k = 0; k < 64; ++k) wreg[k] = W[k * OUT + col];
    float bi = bias[col];
    int stride = gridDim.x * 4;
    for (int n = blockIdx.x * 4 + w; n < n_nodes; n += stride) {
        const float* row = use_hids ? (inbuf + (long)h_ids[n] * 64) : (inbuf + (long)n * 64);
        float xv = row[j];
        if (relu_in) xv = fmaxf(xv, 0.f);
        float acc = bi;
#pragma unroll
        for (int k = 0; k < 64; ++k)
            acc = fmaf(bcastf(xv, k), wreg[k], acc);
        outbuf[(long)n * OUT + col] = acc;
    }
}

// butterfly transpose-reduce over 8-lane group
__device__ __forceinline__ float reduce8(float a0, float a1, float a2, float a3,
                                         float a4, float a5, float a6, float a7, int i) {
    int p1 = i & 1, p2 = (i >> 1) & 1, p3 = (i >> 2) & 1;
    float ka, sb, u0, u1, u2, u3, w0, w1;
    ka = p1 ? a1 : a0; sb = p1 ? a0 : a1; u0 = ka + __shfl_xor(sb, 1, 64);
    ka = p1 ? a3 : a2; sb = p1 ? a2 : a3; u1 = ka + __shfl_xor(sb, 1, 64);
    ka = p1 ? a5 : a4; sb = p1 ? a4 : a5; u2 = ka + __shfl_xor(sb, 1, 64);
    ka = p1 ? a7 : a6; sb = p1 ? a6 : a7; u3 = ka + __shfl_xor(sb, 1, 64);
    ka = p2 ? u1 : u0; sb = p2 ? u0 : u1; w0 = ka + __shfl_xor(sb, 2, 64);
    ka = p2 ? u3 : u2; sb = p2 ? u2 : u3; w1 = ka + __shfl_xor(sb, 2, 64);
    ka = p3 ? w1 : w0; sb = p3 ? w0 : w1;
    return ka + __shfl_xor(sb, 4, 64);
}

// edge1: h1[n] += sum_e nm * bdd(emb[h_ids[src]], w1[rel])   (h1 pre-filled by gemm1)
__global__ __launch_bounds__(256, 4) void
edge1(const float* __restrict__ emb, const float* __restrict__ w1,
      const int* __restrict__ off, const unsigned* __restrict__ packA,
      const float* __restrict__ norm_s, float* __restrict__ h1, int n_nodes) {
    int tid = threadIdx.x;
    int w = tid >> 6, j = tid & 63, i = j & 7;
    int stride = gridDim.x * 4;
    const long woff = (long)j * 8;  // b*64 + i*8
    for (int n = blockIdx.x * 4 + w; n < n_nodes; n += stride) {
        float base = h1[(long)n * 64 + j];  // issue early; arrives during edge loop
        float a0 = 0.f, a1 = 0.f, a2 = 0.f, a3 = 0.f, a4 = 0.f, a5 = 0.f, a6 = 0.f, a7 = 0.f;
        int e0 = off[n], e1v = off[n + 1];
        for (int win = e0; win < e1v; win += 64) {
            int wcnt = e1v - win; if (wcnt > 64) wcnt = 64;
            unsigned u = (j < wcnt) ? packA[win + j] : 0u;
            float nmv = (j < wcnt) ? norm_s[win + j] : 0.f;
            for (int base8 = 0; base8 < wcnt; base8 += 8) {
                int cnt = wcnt - base8; if (cnt > 8) cnt = 8;
                float xs[8];
                int rr[8];
#pragma unroll
                for (int c = 0; c < 8; ++c)
                    if (c < cnt) {
                        int uc = bcasti((int)u, base8 + c);
                        xs[c] = emb[(long)(uc & 0xFFFF) * 64 + j];
                        rr[c] = uc >> 16;
                    }
#pragma unroll
                for (int c = 0; c < 8; ++c)
                    if (c < cnt) {
                        float nm = bcastf(nmv, base8 + c);
                        const float4* w4 = (const float4*)(w1 + (long)rr[c] * 512 + woff);
                        float4 wa = w4[0], wb = w4[1];
                        float xm = xs[c] * nm;
                        a0 = fmaf(xm, wa.x, a0); a1 = fmaf(xm, wa.y, a1);
                        a2 = fmaf(xm, wa.z, a2); a3 = fmaf(xm, wa.w, a3);
                        a4 = fmaf(xm, wb.x, a4); a5 = fmaf(xm, wb.y, a5);
                        a6 = fmaf(xm, wb.z, a6); a7 = fmaf(xm, wb.w, a7);
                    }
            }
        }
        float agg = reduce8(a0, a1, a2, a3, a4, a5, a6, a7, i);
        h1[(long)n * 64 + j] = base + agg;
    }
}

// edge2: out = reparam(h2b[n] + sum_e nm * bdd(relu(h1[src]), w2[rel]))
__global__ __launch_bounds__(256, 4) void
edge2(const float* __restrict__ h1, const float* __restrict__ w2,
      const float* __restrict__ h2b, const float* __restrict__ eps,
      const int* __restrict__ off, const unsigned* __restrict__ packB,
      const float* __restrict__ norm_s, float* __restrict__ out, int n_nodes) {
    int tid = threadIdx.x;
    int w = tid >> 6, j = tid & 63;
    int i = j & 7, b = j >> 3;
    int o1 = b * 16 + i, o2 = o1 + 8;
    int stride = gridDim.x * 4;
    const long woff = (long)j * 16;  // b*128 + i*16
    for (int n = blockIdx.x * 4 + w; n < n_nodes; n += stride) {
        float base1 = h2b[(long)n * 128 + o1];  // issue early
        float base2 = h2b[(long)n * 128 + o2];
        float a[16];
#pragma unroll
        for (int q = 0; q < 16; ++q) a[q] = 0.f;
        int e0 = off[n], e1v = off[n + 1];
        for (int win = e0; win < e1v; win += 64) {
            int wcnt = e1v - win; if (wcnt > 64) wcnt = 64;
            unsigned u = (j < wcnt) ? packB[win + j] : 0u;
            float nmv = (j < wcnt) ? norm_s[win + j] : 0.f;
            for (int base8 = 0; base8 < wcnt; base8 += 8) {
                int cnt = wcnt - base8; if (cnt > 8) cnt = 8;
                float xs[8];
                int rr[8];
#pragma unroll
                for (int c = 0; c < 8; ++c)
                    if (c < cnt) {
                        int uc = bcasti((int)u, base8 + c);
                        xs[c] = fmaxf(h1[(long)(uc & 0xFFFF) * 64 + j], 0.f);
                        rr[c] = uc >> 16;
                    }
#pragma unroll
                for (int c = 0; c < 8; ++c)
                    if (c < cnt) {
                        float nm = bcastf(nmv, base8 + c);
                        const float4* w4 = (const float4*)(w2 + (long)rr[c] * 1024 + woff);
                        float4 wa = w4[0], wb = w4[1], wc = w4[2], wd = w4[3];
                        float xm = xs[c] * nm;
                        a[0] = fmaf(xm, wa.x, a[0]);   a[1] = fmaf(xm, wa.y, a[1]);
                        a[2] = fmaf(xm, wa.z, a[2]);   a[3] = fmaf(xm, wa.w, a[3]);
                        a[4] = fmaf(xm, wb.x, a[4]);   a[5] = fmaf(xm, wb.y, a[5]);
                        a[6] = fmaf(xm, wb.z, a[6]);   a[7] = fmaf(xm, wb.w, a[7]);
                        a[8] = fmaf(xm, wc.x, a[8]);   a[9] = fmaf(xm, wc.y, a[9]);
                        a[10] = fmaf(xm, wc.z, a[10]); a[11] = fmaf(xm, wc.w, a[11]);
                        a[12] = fmaf(xm, wd.x, a[12]); a[13] = fmaf(xm, wd.y, a[13]);
                        a[14] = fmaf(xm, wd.z, a[14]); a[15] = fmaf(xm, wd.w, a[15]);
                    }
            }
        }
        float r1 = reduce8(a[0], a[1], a[2], a[3], a[4], a[5], a[6], a[7], i);
        float r2 = reduce8(a[8], a[9], a[10], a[11], a[12], a[13], a[14], a[15], i);
        float v1 = r1 + base1;  // h2[n, o1]
        float v2 = r2 + base2;  // h2[n, o2]
        // pair m (cols<64, lanes b<4) with raw_v (cols>=64): partner lane j^32
        float p1 = __shfl_xor(v1, 32, 64);
        float p2 = __shfl_xor(v2, 32, 64);
        if (j < 32) {
            long basep = (long)n * 64;
            float sp1 = (p1 > 20.f) ? p1 : log1pf(expf(p1));
            float sp2 = (p2 > 20.f) ? p2 : log1pf(expf(p2));
            out[basep + o1] = fmaf(sqrtf(sp1 + 1e-8f), eps[basep + o1], v1);
            out[basep + o2] = fmaf(sqrtf(sp2 + 1e-8f), eps[basep + o2], v2);
        }
    }
}

extern "C" void kernel_launch(void* const* d_in, const int* in_sizes, int n_in,
                              void* d_out, int out_size, void* d_ws, size_t ws_size,
                              hipStream_t stream) {
    const float* emb   = (const float*)d_in[0];
    const float* norm  = (const float*)d_in[1];
    const float* eps   = (const float*)d_in[2];
    const float* w1    = (const float*)d_in[3];
    const float* lw1   = (const float*)d_in[4];
    const float* b1    = (const float*)d_in[5];
    const float* w2    = (const float*)d_in[6];
    const float* lw2   = (const float*)d_in[7];
    const float* b2    = (const float*)d_in[8];
    const int*   h_ids = (const int*)d_in[9];
    const int*   src   = (const int*)d_in[10];
    const int*   dst   = (const int*)d_in[11];
    const int*   rel   = (const int*)d_in[12];
    float* out = (float*)d_out;

    int n_nodes = in_sizes[0] / 64;   // 50000
    int n_edges = in_sizes[10];       // 400000

    char* ws = (char*)d_ws;
    int*   deg    = (int*)ws;                         ws += (size_t)n_nodes * 4;
    int*   fil    = (int*)ws;                         ws += (size_t)n_nodes * 4;
    int*   off    = (int*)ws;                         ws += (size_t)(n_nodes + 1) * 4;
    float* h1     = (float*)ws;                       ws += (size_t)n_nodes * 64 * 4;
    float* h2b    = (float*)ws;                       ws += (size_t)n_nodes * 128 * 4;
    unsigned* pkA = (unsigned*)ws;                    ws += (size_t)n_edges * 4;
    unsigned* pkB = (unsigned*)ws;                    ws += (size_t)n_edges * 4;
    float* norm_s = (float*)ws;

    int blk = 256;
    // CSR build
    hipMemsetAsync(deg, 0, (size_t)n_nodes * 8, stream);
    hist<<<(n_edges + blk - 1) / blk, blk, 0, stream>>>(dst, deg, n_edges);
    scan_deg<<<1, 1024, 0, stream>>>(deg, off, n_nodes);
    scatter_pack<<<(n_edges + blk - 1) / blk, blk, 0, stream>>>(src, dst, rel, norm, h_ids, off, fil, pkA, pkB, norm_s, n_edges);
    // layer 1: streaming self-loop GEMM -> h1, then edge agg adds in-place
    gemm_sl<<<dim3(1024, 1), blk, 0, stream>>>(emb, h_ids, 1, 0, lw1, b1, h1, n_nodes, 64);
    edge1<<<3072, blk, 0, stream>>>(emb, w1, off, pkA, norm_s, h1, n_nodes);
    // layer 2: streaming self-loop GEMM -> h2b, then edge agg + fused reparam -> out
    gemm_sl<<<dim3(1024, 2), blk, 0, stream>>>(h1, h_ids, 0, 1, lw2, b2, h2b, n_nodes, 128);
    edge2<<<3072, blk, 0, stream>>>(h1, w2, h2b, eps, off, pkB, norm_s, out, n_nodes);
}

// Round 8
// 356.292 us; speedup vs baseline: 1.2314x; 1.2314x over previous
//
#include <hip/hip_runtime.h>
#include <math.h>

// KGVAE: 2-layer RelGraphConv (bdd) + reparameterize, R8.
// bf16 weight tables + bf16 relu(h1) gather copy (halve L2/gather bytes),
// gemm1 fused into edge1 (lw1 column in VGPRs), multi-block scan.
// ws: deg[N] fil[N] | off[N+1] | bsum[256] | h1[N*64]f32 | h1h[N*64]bf16 |
//     h2b[N*128]f32 | pkA[E] | pkB[E] | norm_s[E] | w1h[R*512]bf16 | w2h[R*1024]bf16

__device__ __forceinline__ int bcasti(int v, int l) {
    return __builtin_amdgcn_readlane(v, l);
}
__device__ __forceinline__ float bcastf(float v, int l) {
    return __int_as_float(__builtin_amdgcn_readlane(__float_as_int(v), l));
}
__device__ __forceinline__ unsigned short f2bf(float f) {  // RTN bf16
    unsigned u = __float_as_uint(f);
    return (unsigned short)((u + 0x7FFFu + ((u >> 16) & 1u)) >> 16);
}
__device__ __forceinline__ float bfl(unsigned d) {  // low half -> f32
    return __uint_as_float(d << 16);
}
__device__ __forceinline__ float bfh(unsigned d) {  // high half -> f32
    return __uint_as_float(d & 0xFFFF0000u);
}

__global__ void hist(const int* __restrict__ dst, int* __restrict__ deg, int e) {
    int i = blockIdx.x * blockDim.x + threadIdx.x;
    if (i < e) atomicAdd(&deg[dst[i]], 1);
}

// ---- 3-pass scan: deg[N] -> off[N+1] (exclusive), off[N] = total ----
__global__ void scan_part(const int* __restrict__ deg, int* __restrict__ bsum, int n) {
    __shared__ int sm[256];
    int t = threadIdx.x, g = blockIdx.x * 256 + t;
    sm[t] = (g < n) ? deg[g] : 0;
    __syncthreads();
    for (int d = 128; d > 0; d >>= 1) {
        if (t < d) sm[t] += sm[t + d];
        __syncthreads();
    }
    if (t == 0) bsum[blockIdx.x] = sm[0];
}

__global__ void scan_bsum(int* __restrict__ bsum, int* __restrict__ off, int nb, int n) {
    __shared__ int sm[256];
    int t = threadIdx.x;
    int v = (t < nb) ? bsum[t] : 0;
    sm[t] = v;
    __syncthreads();
    for (int d = 1; d < 256; d <<= 1) {
        int u = (t >= d) ? sm[t - d] : 0;
        __syncthreads();
        sm[t] += u;
        __syncthreads();
    }
    if (t < nb) bsum[t] = sm[t] - v;   // exclusive
    if (t == 255) off[n] = sm[255];    // total
}

__global__ void scan_write(const int* __restrict__ deg, const int* __restrict__ bsum,
                           int* __restrict__ off, int n) {
    __shared__ int sm[256];
    int t = threadIdx.x, g = blockIdx.x * 256 + t;
    int v = (g < n) ? deg[g] : 0;
    sm[t] = v;
    __syncthreads();
    for (int d = 1; d < 256; d <<= 1) {
        int u = (t >= d) ? sm[t - d] : 0;
        __syncthreads();
        sm[t] += u;
        __syncthreads();
    }
    if (g < n) off[g] = bsum[blockIdx.x] + sm[t] - v;
}

// packA = h_ids[src] | rel<<16 ; packB = src | rel<<16
__global__ void scatter_pack(const int* __restrict__ src, const int* __restrict__ dst,
                             const int* __restrict__ rel, const float* __restrict__ norm,
                             const int* __restrict__ h_ids, const int* __restrict__ off,
                             int* __restrict__ fil, unsigned* __restrict__ packA,
                             unsigned* __restrict__ packB, float* __restrict__ norm_s, int e) {
    int i = blockIdx.x * blockDim.x + threadIdx.x;
    if (i >= e) return;
    int d = dst[i];
    int p = off[d] + atomicAdd(&fil[d], 1);
    unsigned rhi = (unsigned)rel[i] << 16;
    int s = src[i];
    packA[p] = (unsigned)h_ids[s] | rhi;
    packB[p] = (unsigned)s | rhi;
    norm_s[p] = norm[i];
}

// convert w1,w2 to bf16 tables
__global__ void cvt_w(const float* __restrict__ w1, const float* __restrict__ w2,
                      unsigned short* __restrict__ w1h, unsigned short* __restrict__ w2h,
                      int n1, int n2) {
    int i = blockIdx.x * blockDim.x + threadIdx.x;
    if (i < n1) w1h[i] = f2bf(w1[i]);
    else if (i < n1 + n2) w2h[i - n1] = f2bf(w2[i - n1]);
}

// butterfly transpose-reduce over 8-lane group
__device__ __forceinline__ float reduce8(float a0, float a1, float a2, float a3,
                                         float a4, float a5, float a6, float a7, int i) {
    int p1 = i & 1, p2 = (i >> 1) & 1, p3 = (i >> 2) & 1;
    float ka, sb, u0, u1, u2, u3, w0, w1;
    ka = p1 ? a1 : a0; sb = p1 ? a0 : a1; u0 = ka + __shfl_xor(sb, 1, 64);
    ka = p1 ? a3 : a2; sb = p1 ? a2 : a3; u1 = ka + __shfl_xor(sb, 1, 64);
    ka = p1 ? a5 : a4; sb = p1 ? a4 : a5; u2 = ka + __shfl_xor(sb, 1, 64);
    ka = p1 ? a7 : a6; sb = p1 ? a6 : a7; u3 = ka + __shfl_xor(sb, 1, 64);
    ka = p2 ? u1 : u0; sb = p2 ? u0 : u1; w0 = ka + __shfl_xor(sb, 2, 64);
    ka = p2 ? u3 : u2; sb = p2 ? u2 : u3; w1 = ka + __shfl_xor(sb, 2, 64);
    ka = p3 ? w1 : w0; sb = p3 ? w0 : w1;
    return ka + __shfl_xor(sb, 4, 64);
}

// edge1f: h1[n] = b1 + emb[h_ids[n]]@lw1 (in-register column GEMV)
//                + sum_e nm * bdd(emb[h_ids[src]], w1h[rel])
// also writes h1h = bf16(relu(h1)) for edge2's gathers.
__global__ __launch_bounds__(256) void
edge1f(const float* __restrict__ emb, const int* __restrict__ h_ids,
       const unsigned short* __restrict__ w1h, const float* __restrict__ lw1,
       const float* __restrict__ b1, const int* __restrict__ off,
       const unsigned* __restrict__ packA, const float* __restrict__ norm_s,
       float* __restrict__ h1, unsigned short* __restrict__ h1h, int n_nodes) {
    int tid = threadIdx.x;
    int w = tid >> 6, j = tid & 63, i = j & 7;
    float wreg[64];
#pragma unroll
    for (int k = 0; k < 64; ++k) wreg[k] = lw1[k * 64 + j];  // column j
    float b1j = b1[j];
    int stride = gridDim.x * 4;
    const long woff = (long)j * 8;  // (b*64 + i*8) halves
    for (int n = blockIdx.x * 4 + w; n < n_nodes; n += stride) {
        float xv = emb[(long)h_ids[n] * 64 + j];
        float a0 = 0.f, a1 = 0.f, a2 = 0.f, a3 = 0.f, a4 = 0.f, a5 = 0.f, a6 = 0.f, a7 = 0.f;
        int e0 = off[n], e1v = off[n + 1];
        for (int win = e0; win < e1v; win += 64) {
            int wcnt = e1v - win; if (wcnt > 64) wcnt = 64;
            unsigned u = (j < wcnt) ? packA[win + j] : 0u;
            float nmv = (j < wcnt) ? norm_s[win + j] : 0.f;
            for (int base8 = 0; base8 < wcnt; base8 += 8) {
                int cnt = wcnt - base8; if (cnt > 8) cnt = 8;
                float xs[8];
                int rr[8];
#pragma unroll
                for (int c = 0; c < 8; ++c)
                    if (c < cnt) {
                        int uc = bcasti((int)u, base8 + c);
                        xs[c] = emb[(long)(uc & 0xFFFF) * 64 + j];
                        rr[c] = uc >> 16;
                    }
#pragma unroll
                for (int c = 0; c < 8; ++c)
                    if (c < cnt) {
                        float nm = bcastf(nmv, base8 + c);
                        const uint4* w4 = (const uint4*)(w1h + (long)rr[c] * 512 + woff);
                        uint4 wd = *w4;  // 8 bf16 weights
                        float xm = xs[c] * nm;
                        a0 = fmaf(xm, bfl(wd.x), a0); a1 = fmaf(xm, bfh(wd.x), a1);
                        a2 = fmaf(xm, bfl(wd.y), a2); a3 = fmaf(xm, bfh(wd.y), a3);
                        a4 = fmaf(xm, bfl(wd.z), a4); a5 = fmaf(xm, bfh(wd.z), a5);
                        a6 = fmaf(xm, bfl(wd.w), a6); a7 = fmaf(xm, bfh(wd.w), a7);
                    }
            }
        }
        float agg = reduce8(a0, a1, a2, a3, a4, a5, a6, a7, i);
        // self-loop GEMV from register column
        float sacc = b1j;
#pragma unroll
        for (int k = 0; k < 64; ++k)
            sacc = fmaf(bcastf(xv, k), wreg[k], sacc);
        float val = sacc + agg;
        long p = (long)n * 64 + j;
        h1[p] = val;
        h1h[p] = f2bf(fmaxf(val, 0.f));
    }
}

// gemm2: h2b[n][col] = b2[col] + sum_k relu(h1[n][k]) * lw2[k][col]
__global__ __launch_bounds__(256) void
gemm2(const float* __restrict__ h1, const float* __restrict__ lw2,
      const float* __restrict__ b2, float* __restrict__ h2b, int n_nodes) {
    int tid = threadIdx.x;
    int w = tid >> 6, j = tid & 63;
    int col = blockIdx.y * 64 + j;
    float wreg[64];
#pragma unroll
    for (int k = 0; k < 64; ++k) wreg[k] = lw2[k * 128 + col];
    float bi = b2[col];
    int stride = gridDim.x * 4;
    for (int n = blockIdx.x * 4 + w; n < n_nodes; n += stride) {
        float xv = fmaxf(h1[(long)n * 64 + j], 0.f);
        float acc = bi;
#pragma unroll
        for (int k = 0; k < 64; ++k)
            acc = fmaf(bcastf(xv, k), wreg[k], acc);
        h2b[(long)n * 128 + col] = acc;
    }
}

// edge2: out = reparam(h2b[n] + sum_e nm * bdd(bf16relu(h1[src]), w2h[rel]))
__global__ __launch_bounds__(256) void
edge2(const unsigned short* __restrict__ h1h, const unsigned short* __restrict__ w2h,
      const float* __restrict__ h2b, const float* __restrict__ eps,
      const int* __restrict__ off, const unsigned* __restrict__ packB,
      const float* __restrict__ norm_s, float* __restrict__ out, int n_nodes) {
    int tid = threadIdx.x;
    int w = tid >> 6, j = tid & 63;
    int i = j & 7, b = j >> 3;
    int o1 = b * 16 + i, o2 = o1 + 8;
    int stride = gridDim.x * 4;
    const long woff = (long)j * 16;  // (b*128 + i*16) halves
    for (int n = blockIdx.x * 4 + w; n < n_nodes; n += stride) {
        float base1 = h2b[(long)n * 128 + o1];
        float base2 = h2b[(long)n * 128 + o2];
        float a[16];
#pragma unroll
        for (int q = 0; q < 16; ++q) a[q] = 0.f;
        int e0 = off[n], e1v = off[n + 1];
        for (int win = e0; win < e1v; win += 64) {
            int wcnt = e1v - win; if (wcnt > 64) wcnt = 64;
            unsigned u = (j < wcnt) ? packB[win + j] : 0u;
            float nmv = (j < wcnt) ? norm_s[win + j] : 0.f;
            for (int base8 = 0; base8 < wcnt; base8 += 8) {
                int cnt = wcnt - base8; if (cnt > 8) cnt = 8;
                float xs[8];
                int rr[8];
#pragma unroll
                for (int c = 0; c < 8; ++c)
                    if (c < cnt) {
                        int uc = bcasti((int)u, base8 + c);
                        xs[c] = __uint_as_float((unsigned)h1h[(long)(uc & 0xFFFF) * 64 + j] << 16);
                        rr[c] = uc >> 16;
                    }
#pragma unroll
                for (int c = 0; c < 8; ++c)
                    if (c < cnt) {
                        float nm = bcastf(nmv, base8 + c);
                        const uint4* w4 = (const uint4*)(w2h + (long)rr[c] * 1024 + woff);
                        uint4 wa = w4[0], wb = w4[1];  // 16 bf16 weights
                        float xm = xs[c] * nm;
                        a[0] = fmaf(xm, bfl(wa.x), a[0]);   a[1] = fmaf(xm, bfh(wa.x), a[1]);
                        a[2] = fmaf(xm, bfl(wa.y), a[2]);   a[3] = fmaf(xm, bfh(wa.y), a[3]);
                        a[4] = fmaf(xm, bfl(wa.z), a[4]);   a[5] = fmaf(xm, bfh(wa.z), a[5]);
                        a[6] = fmaf(xm, bfl(wa.w), a[6]);   a[7] = fmaf(xm, bfh(wa.w), a[7]);
                        a[8] = fmaf(xm, bfl(wb.x), a[8]);   a[9] = fmaf(xm, bfh(wb.x), a[9]);
                        a[10] = fmaf(xm, bfl(wb.y), a[10]); a[11] = fmaf(xm, bfh(wb.y), a[11]);
                        a[12] = fmaf(xm, bfl(wb.z), a[12]); a[13] = fmaf(xm, bfh(wb.z), a[13]);
                        a[14] = fmaf(xm, bfl(wb.w), a[14]); a[15] = fmaf(xm, bfh(wb.w), a[15]);
                    }
            }
        }
        float r1 = reduce8(a[0], a[1], a[2], a[3], a[4], a[5], a[6], a[7], i);
        float r2 = reduce8(a[8], a[9], a[10], a[11], a[12], a[13], a[14], a[15], i);
        float v1 = r1 + base1;  // h2[n, o1]
        float v2 = r2 + base2;  // h2[n, o2]
        float p1 = __shfl_xor(v1, 32, 64);
        float p2 = __shfl_xor(v2, 32, 64);
        if (j < 32) {
            long basep = (long)n * 64;
            float sp1 = (p1 > 20.f) ? p1 : log1pf(expf(p1));
            float sp2 = (p2 > 20.f) ? p2 : log1pf(expf(p2));
            out[basep + o1] = fmaf(sqrtf(sp1 + 1e-8f), eps[basep + o1], v1);
            out[basep + o2] = fmaf(sqrtf(sp2 + 1e-8f), eps[basep + o2], v2);
        }
    }
}

extern "C" void kernel_launch(void* const* d_in, const int* in_sizes, int n_in,
                              void* d_out, int out_size, void* d_ws, size_t ws_size,
                              hipStream_t stream) {
    const float* emb   = (const float*)d_in[0];
    const float* norm  = (const float*)d_in[1];
    const float* eps   = (const float*)d_in[2];
    const float* w1    = (const float*)d_in[3];
    const float* lw1   = (const float*)d_in[4];
    const float* b1    = (const float*)d_in[5];
    const float* w2    = (const float*)d_in[6];
    const float* lw2   = (const float*)d_in[7];
    const float* b2    = (const float*)d_in[8];
    const int*   h_ids = (const int*)d_in[9];
    const int*   src   = (const int*)d_in[10];
    const int*   dst   = (const int*)d_in[11];
    const int*   rel   = (const int*)d_in[12];
    float* out = (float*)d_out;

    int n_nodes = in_sizes[0] / 64;   // 50000
    int n_edges = in_sizes[10];       // 400000
    int nw1 = in_sizes[3];            // 200*512
    int nw2 = in_sizes[6];            // 200*1024

    char* ws = (char*)d_ws;
    int*   deg    = (int*)ws;                         ws += (size_t)n_nodes * 4;
    int*   fil    = (int*)ws;                         ws += (size_t)n_nodes * 4;
    int*   off    = (int*)ws;                         ws += (size_t)(n_nodes + 1) * 4;
    int*   bsum   = (int*)ws;                         ws += 256 * 4;
    float* h1     = (float*)ws;                       ws += (size_t)n_nodes * 64 * 4;
    unsigned short* h1h = (unsigned short*)ws;        ws += (size_t)n_nodes * 64 * 2;
    float* h2b    = (float*)ws;                       ws += (size_t)n_nodes * 128 * 4;
    unsigned* pkA = (unsigned*)ws;                    ws += (size_t)n_edges * 4;
    unsigned* pkB = (unsigned*)ws;                    ws += (size_t)n_edges * 4;
    float* norm_s = (float*)ws;                       ws += (size_t)n_edges * 4;
    unsigned short* w1h = (unsigned short*)ws;        ws += (size_t)nw1 * 2;
    unsigned short* w2h = (unsigned short*)ws;

    int blk = 256;
    int nb = (n_nodes + 255) / 256;   // 196 scan blocks
    // CSR build + weight conversion
    hipMemsetAsync(deg, 0, (size_t)n_nodes * 8, stream);
    cvt_w<<<(nw1 + nw2 + blk - 1) / blk, blk, 0, stream>>>(w1, w2, w1h, w2h, nw1, nw2);
    hist<<<(n_edges + blk - 1) / blk, blk, 0, stream>>>(dst, deg, n_edges);
    scan_part<<<nb, 256, 0, stream>>>(deg, bsum, n_nodes);
    scan_bsum<<<1, 256, 0, stream>>>(bsum, off, nb, n_nodes);
    scan_write<<<nb, 256, 0, stream>>>(deg, bsum, off, n_nodes);
    scatter_pack<<<(n_edges + blk - 1) / blk, blk, 0, stream>>>(src, dst, rel, norm, h_ids, off, fil, pkA, pkB, norm_s, n_edges);
    // layer 1 (fused self-loop + edges), layer 2 (gemm then edges+reparam)
    edge1f<<<1024, blk, 0, stream>>>(emb, h_ids, w1h, lw1, b1, off, pkA, norm_s, h1, h1h, n_nodes);
    gemm2<<<dim3(1024, 2), blk, 0, stream>>>(h1, lw2, b2, h2b, n_nodes);
    edge2<<<3072, blk, 0, stream>>>(h1h, w2h, h2b, eps, off, pkB, norm_s, out, n_nodes);
}

// Round 9
// 351.868 us; speedup vs baseline: 1.2469x; 1.0126x over previous
//
#include <hip/hip_runtime.h>
#include <math.h>

// KGVAE: 2-layer RelGraphConv (bdd) + reparameterize, R9.
// MFMA self-loop GEMMs (16x16x32 bf16), 16-deep gather batches in edge
// kernels, grid 4096, edge1 writes bf16-only h1.
// ws: h1b[N*64]f32 | h2b[N*128]f32 | h1h[N*64]bf16 | w1h | w2h | pkA | pkB |
//     norm_s | deg | fil | off | bsum

typedef __attribute__((ext_vector_type(8))) short bf16x8;
typedef __attribute__((ext_vector_type(4))) float f32x4;

__device__ __forceinline__ int bcasti(int v, int l) {
    return __builtin_amdgcn_readlane(v, l);
}
__device__ __forceinline__ float bcastf(float v, int l) {
    return __int_as_float(__builtin_amdgcn_readlane(__float_as_int(v), l));
}
__device__ __forceinline__ unsigned short f2bf(float f) {  // RTN bf16
    unsigned u = __float_as_uint(f);
    return (unsigned short)((u + 0x7FFFu + ((u >> 16) & 1u)) >> 16);
}
__device__ __forceinline__ float bfl(unsigned d) { return __uint_as_float(d << 16); }
__device__ __forceinline__ float bfh(unsigned d) { return __uint_as_float(d & 0xFFFF0000u); }

__global__ void hist(const int* __restrict__ dst, int* __restrict__ deg, int e) {
    int i = blockIdx.x * blockDim.x + threadIdx.x;
    if (i < e) atomicAdd(&deg[dst[i]], 1);
}

__global__ void scan_part(const int* __restrict__ deg, int* __restrict__ bsum, int n) {
    __shared__ int sm[256];
    int t = threadIdx.x, g = blockIdx.x * 256 + t;
    sm[t] = (g < n) ? deg[g] : 0;
    __syncthreads();
    for (int d = 128; d > 0; d >>= 1) {
        if (t < d) sm[t] += sm[t + d];
        __syncthreads();
    }
    if (t == 0) bsum[blockIdx.x] = sm[0];
}

__global__ void scan_bsum(int* __restrict__ bsum, int* __restrict__ off, int nb, int n) {
    __shared__ int sm[256];
    int t = threadIdx.x;
    int v = (t < nb) ? bsum[t] : 0;
    sm[t] = v;
    __syncthreads();
    for (int d = 1; d < 256; d <<= 1) {
        int u = (t >= d) ? sm[t - d] : 0;
        __syncthreads();
        sm[t] += u;
        __syncthreads();
    }
    if (t < nb) bsum[t] = sm[t] - v;
    if (t == 255) off[n] = sm[255];
}

__global__ void scan_write(const int* __restrict__ deg, const int* __restrict__ bsum,
                           int* __restrict__ off, int n) {
    __shared__ int sm[256];
    int t = threadIdx.x, g = blockIdx.x * 256 + t;
    int v = (g < n) ? deg[g] : 0;
    sm[t] = v;
    __syncthreads();
    for (int d = 1; d < 256; d <<= 1) {
        int u = (t >= d) ? sm[t - d] : 0;
        __syncthreads();
        sm[t] += u;
        __syncthreads();
    }
    if (g < n) off[g] = bsum[blockIdx.x] + sm[t] - v;
}

__global__ void scatter_pack(const int* __restrict__ src, const int* __restrict__ dst,
                             const int* __restrict__ rel, const float* __restrict__ norm,
                             const int* __restrict__ h_ids, const int* __restrict__ off,
                             int* __restrict__ fil, unsigned* __restrict__ packA,
                             unsigned* __restrict__ packB, float* __restrict__ norm_s, int e) {
    int i = blockIdx.x * blockDim.x + threadIdx.x;
    if (i >= e) return;
    int d = dst[i];
    int p = off[d] + atomicAdd(&fil[d], 1);
    unsigned rhi = (unsigned)rel[i] << 16;
    int s = src[i];
    packA[p] = (unsigned)h_ids[s] | rhi;
    packB[p] = (unsigned)s | rhi;
    norm_s[p] = norm[i];
}

__global__ void cvt_w(const float* __restrict__ w1, const float* __restrict__ w2,
                      unsigned short* __restrict__ w1h, unsigned short* __restrict__ w2h,
                      int n1, int n2) {
    int i = blockIdx.x * blockDim.x + threadIdx.x;
    if (i < n1) w1h[i] = f2bf(w1[i]);
    else if (i < n1 + n2) w2h[i - n1] = f2bf(w2[i - n1]);
}

// gemm1: h1b[16-row tile] = b1 + bf16(emb[h_ids[row]]) @ bf16(lw1)   (MFMA)
// block = 4 waves; wave w = col-tile w (cols w*16..w*16+15); K=64 = 2 MFMA.
__global__ __launch_bounds__(256) void
gemm1_mfma(const float* __restrict__ emb, const int* __restrict__ h_ids,
           const float* __restrict__ lw1, const float* __restrict__ b1,
           float* __restrict__ h1b, int n_nodes) {
    int w = threadIdx.x >> 6, l = threadIdx.x & 63;
    int lr = l & 15, lq = l >> 4;
    int rt = blockIdx.x;
    // B-frags: n = w*16+lr, k = kb*32 + lq*8 + j
    bf16x8 bfr[2];
    int coln = w * 16 + lr;
#pragma unroll
    for (int kb = 0; kb < 2; ++kb)
#pragma unroll
        for (int jj = 0; jj < 8; ++jj)
            bfr[kb][jj] = (short)f2bf(lw1[(kb * 32 + lq * 8 + jj) * 64 + coln]);
    // A-frags: row = rt*16+lr (gather via h_ids), k = kb*32 + lq*8 + j
    int nrow = rt * 16 + lr;
    if (nrow >= n_nodes) nrow = n_nodes - 1;
    const float* arow = emb + (long)h_ids[nrow] * 64 + lq * 8;
    bf16x8 af0, af1;
#pragma unroll
    for (int jj = 0; jj < 8; ++jj) {
        af0[jj] = (short)f2bf(arow[jj]);
        af1[jj] = (short)f2bf(arow[32 + jj]);
    }
    f32x4 acc = {0.f, 0.f, 0.f, 0.f};
    acc = __builtin_amdgcn_mfma_f32_16x16x32_bf16(af0, bfr[0], acc, 0, 0, 0);
    acc = __builtin_amdgcn_mfma_f32_16x16x32_bf16(af1, bfr[1], acc, 0, 0, 0);
    float bb = b1[coln];
#pragma unroll
    for (int r = 0; r < 4; ++r) {
        int row = rt * 16 + lq * 4 + r;
        if (row < n_nodes) h1b[(long)row * 64 + coln] = acc[r] + bb;
    }
}

// gemm2: h2b[16-row tile] = b2 + h1h @ bf16(lw2)  (MFMA, N=128 -> 8 col tiles,
// wave w handles col-tiles 2w, 2w+1)
__global__ __launch_bounds__(256) void
gemm2_mfma(const unsigned short* __restrict__ h1h, const float* __restrict__ lw2,
           const float* __restrict__ b2, float* __restrict__ h2b, int n_nodes) {
    int w = threadIdx.x >> 6, l = threadIdx.x & 63;
    int lr = l & 15, lq = l >> 4;
    int rt = blockIdx.x;
    bf16x8 bfr[2][2];
    int col0 = (2 * w) * 16 + lr, col1 = (2 * w + 1) * 16 + lr;
#pragma unroll
    for (int kb = 0; kb < 2; ++kb)
#pragma unroll
        for (int jj = 0; jj < 8; ++jj) {
            int k = kb * 32 + lq * 8 + jj;
            bfr[0][kb][jj] = (short)f2bf(lw2[k * 128 + col0]);
            bfr[1][kb][jj] = (short)f2bf(lw2[k * 128 + col1]);
        }
    int nrow = rt * 16 + lr;
    if (nrow >= n_nodes) nrow = n_nodes - 1;
    const bf16x8* ap = (const bf16x8*)(h1h + (long)nrow * 64 + lq * 8);
    bf16x8 af0 = ap[0];   // k 0..31 slice (lq*8 .. lq*8+7)
    bf16x8 af1 = *(const bf16x8*)(h1h + (long)nrow * 64 + 32 + lq * 8);
    f32x4 acc0 = {0.f, 0.f, 0.f, 0.f}, acc1 = {0.f, 0.f, 0.f, 0.f};
    acc0 = __builtin_amdgcn_mfma_f32_16x16x32_bf16(af0, bfr[0][0], acc0, 0, 0, 0);
    acc0 = __builtin_amdgcn_mfma_f32_16x16x32_bf16(af1, bfr[0][1], acc0, 0, 0, 0);
    acc1 = __builtin_amdgcn_mfma_f32_16x16x32_bf16(af0, bfr[1][0], acc1, 0, 0, 0);
    acc1 = __builtin_amdgcn_mfma_f32_16x16x32_bf16(af1, bfr[1][1], acc1, 0, 0, 0);
    float bb0 = b2[col0], bb1 = b2[col1];
#pragma unroll
    for (int r = 0; r < 4; ++r) {
        int row = rt * 16 + lq * 4 + r;
        if (row < n_nodes) {
            h2b[(long)row * 128 + col0] = acc0[r] + bb0;
            h2b[(long)row * 128 + col1] = acc1[r] + bb1;
        }
    }
}

// butterfly transpose-reduce over 8-lane group
__device__ __forceinline__ float reduce8(float a0, float a1, float a2, float a3,
                                         float a4, float a5, float a6, float a7, int i) {
    int p1 = i & 1, p2 = (i >> 1) & 1, p3 = (i >> 2) & 1;
    float ka, sb, u0, u1, u2, u3, w0, w1;
    ka = p1 ? a1 : a0; sb = p1 ? a0 : a1; u0 = ka + __shfl_xor(sb, 1, 64);
    ka = p1 ? a3 : a2; sb = p1 ? a2 : a3; u1 = ka + __shfl_xor(sb, 1, 64);
    ka = p1 ? a5 : a4; sb = p1 ? a4 : a5; u2 = ka + __shfl_xor(sb, 1, 64);
    ka = p1 ? a7 : a6; sb = p1 ? a6 : a7; u3 = ka + __shfl_xor(sb, 1, 64);
    ka = p2 ? u1 : u0; sb = p2 ? u0 : u1; w0 = ka + __shfl_xor(sb, 2, 64);
    ka = p2 ? u3 : u2; sb = p2 ? u2 : u3; w1 = ka + __shfl_xor(sb, 2, 64);
    ka = p3 ? w1 : w0; sb = p3 ? w0 : w1;
    return ka + __shfl_xor(sb, 4, 64);
}

// edge1: h1h[n] = bf16(relu(h1b[n] + sum_e nm * bdd(emb[h_ids[src]], w1h[rel])))
__global__ __launch_bounds__(256) void
edge1(const float* __restrict__ emb, const unsigned short* __restrict__ w1h,
      const float* __restrict__ h1b, const int* __restrict__ off,
      const unsigned* __restrict__ packA, const float* __restrict__ norm_s,
      unsigned short* __restrict__ h1h, int n_nodes) {
    int tid = threadIdx.x;
    int w = tid >> 6, j = tid & 63, i = j & 7;
    int stride = gridDim.x * 4;
    const long woff = (long)j * 8;
    for (int n = blockIdx.x * 4 + w; n < n_nodes; n += stride) {
        float base = h1b[(long)n * 64 + j];  // issue early
        float a0 = 0.f, a1 = 0.f, a2 = 0.f, a3 = 0.f, a4 = 0.f, a5 = 0.f, a6 = 0.f, a7 = 0.f;
        int e0 = off[n], e1v = off[n + 1];
        for (int win = e0; win < e1v; win += 64) {
            int wcnt = e1v - win; if (wcnt > 64) wcnt = 64;
            unsigned u = (j < wcnt) ? packA[win + j] : 0u;
            float nmv = (j < wcnt) ? norm_s[win + j] : 0.f;
            for (int b16 = 0; b16 < wcnt; b16 += 16) {
                int cnt = wcnt - b16; if (cnt > 16) cnt = 16;
                float xs[16];
                int rr[16];
#pragma unroll
                for (int c = 0; c < 16; ++c)
                    if (c < cnt) {
                        int uc = bcasti((int)u, b16 + c);
                        xs[c] = emb[(long)(uc & 0xFFFF) * 64 + j];
                        rr[c] = uc >> 16;
                    }
#pragma unroll
                for (int c = 0; c < 16; ++c)
                    if (c < cnt) {
                        float nm = bcastf(nmv, b16 + c);
                        const uint4* w4 = (const uint4*)(w1h + (long)rr[c] * 512 + woff);
                        uint4 wd = *w4;
                        float xm = xs[c] * nm;
                        a0 = fmaf(xm, bfl(wd.x), a0); a1 = fmaf(xm, bfh(wd.x), a1);
                        a2 = fmaf(xm, bfl(wd.y), a2); a3 = fmaf(xm, bfh(wd.y), a3);
                        a4 = fmaf(xm, bfl(wd.z), a4); a5 = fmaf(xm, bfh(wd.z), a5);
                        a6 = fmaf(xm, bfl(wd.w), a6); a7 = fmaf(xm, bfh(wd.w), a7);
                    }
            }
        }
        float agg = reduce8(a0, a1, a2, a3, a4, a5, a6, a7, i);
        h1h[(long)n * 64 + j] = f2bf(fmaxf(base + agg, 0.f));
    }
}

// edge2: out = reparam(h2b[n] + sum_e nm * bdd(h1h[src], w2h[rel]))
__global__ __launch_bounds__(256) void
edge2(const unsigned short* __restrict__ h1h, const unsigned short* __restrict__ w2h,
      const float* __restrict__ h2b, const float* __restrict__ eps,
      const int* __restrict__ off, const unsigned* __restrict__ packB,
      const float* __restrict__ norm_s, float* __restrict__ out, int n_nodes) {
    int tid = threadIdx.x;
    int w = tid >> 6, j = tid & 63;
    int i = j & 7, b = j >> 3;
    int o1 = b * 16 + i, o2 = o1 + 8;
    int stride = gridDim.x * 4;
    const long woff = (long)j * 16;
    for (int n = blockIdx.x * 4 + w; n < n_nodes; n += stride) {
        float base1 = h2b[(long)n * 128 + o1];
        float base2 = h2b[(long)n * 128 + o2];
        float a[16];
#pragma unroll
        for (int q = 0; q < 16; ++q) a[q] = 0.f;
        int e0 = off[n], e1v = off[n + 1];
        for (int win = e0; win < e1v; win += 64) {
            int wcnt = e1v - win; if (wcnt > 64) wcnt = 64;
            unsigned u = (j < wcnt) ? packB[win + j] : 0u;
            float nmv = (j < wcnt) ? norm_s[win + j] : 0.f;
            for (int b16 = 0; b16 < wcnt; b16 += 16) {
                int cnt = wcnt - b16; if (cnt > 16) cnt = 16;
                float xs[16];
                int rr[16];
#pragma unroll
                for (int c = 0; c < 16; ++c)
                    if (c < cnt) {
                        int uc = bcasti((int)u, b16 + c);
                        xs[c] = __uint_as_float((unsigned)h1h[(long)(uc & 0xFFFF) * 64 + j] << 16);
                        rr[c] = uc >> 16;
                    }
#pragma unroll
                for (int c = 0; c < 16; ++c)
                    if (c < cnt) {
                        float nm = bcastf(nmv, b16 + c);
                        const uint4* w4 = (const uint4*)(w2h + (long)rr[c] * 1024 + woff);
                        uint4 wa = w4[0], wb = w4[1];
                        float xm = xs[c] * nm;
                        a[0] = fmaf(xm, bfl(wa.x), a[0]);   a[1] = fmaf(xm, bfh(wa.x), a[1]);
                        a[2] = fmaf(xm, bfl(wa.y), a[2]);   a[3] = fmaf(xm, bfh(wa.y), a[3]);
                        a[4] = fmaf(xm, bfl(wa.z), a[4]);   a[5] = fmaf(xm, bfh(wa.z), a[5]);
                        a[6] = fmaf(xm, bfl(wa.w), a[6]);   a[7] = fmaf(xm, bfh(wa.w), a[7]);
                        a[8] = fmaf(xm, bfl(wb.x), a[8]);   a[9] = fmaf(xm, bfh(wb.x), a[9]);
                        a[10] = fmaf(xm, bfl(wb.y), a[10]); a[11] = fmaf(xm, bfh(wb.y), a[11]);
                        a[12] = fmaf(xm, bfl(wb.z), a[12]); a[13] = fmaf(xm, bfh(wb.z), a[13]);
                        a[14] = fmaf(xm, bfl(wb.w), a[14]); a[15] = fmaf(xm, bfh(wb.w), a[15]);
                    }
            }
        }
        float r1 = reduce8(a[0], a[1], a[2], a[3], a[4], a[5], a[6], a[7], i);
        float r2 = reduce8(a[8], a[9], a[10], a[11], a[12], a[13], a[14], a[15], i);
        float v1 = r1 + base1;
        float v2 = r2 + base2;
        float p1 = __shfl_xor(v1, 32, 64);
        float p2 = __shfl_xor(v2, 32, 64);
        if (j < 32) {
            long basep = (long)n * 64;
            float sp1 = (p1 > 20.f) ? p1 : log1pf(expf(p1));
            float sp2 = (p2 > 20.f) ? p2 : log1pf(expf(p2));
            out[basep + o1] = fmaf(sqrtf(sp1 + 1e-8f), eps[basep + o1], v1);
            out[basep + o2] = fmaf(sqrtf(sp2 + 1e-8f), eps[basep + o2], v2);
        }
    }
}

extern "C" void kernel_launch(void* const* d_in, const int* in_sizes, int n_in,
                              void* d_out, int out_size, void* d_ws, size_t ws_size,
                              hipStream_t stream) {
    const float* emb   = (const float*)d_in[0];
    const float* norm  = (const float*)d_in[1];
    const float* eps   = (const float*)d_in[2];
    const float* w1    = (const float*)d_in[3];
    const float* lw1   = (const float*)d_in[4];
    const float* b1    = (const float*)d_in[5];
    const float* w2    = (const float*)d_in[6];
    const float* lw2   = (const float*)d_in[7];
    const float* b2    = (const float*)d_in[8];
    const int*   h_ids = (const int*)d_in[9];
    const int*   src   = (const int*)d_in[10];
    const int*   dst   = (const int*)d_in[11];
    const int*   rel   = (const int*)d_in[12];
    float* out = (float*)d_out;

    int n_nodes = in_sizes[0] / 64;   // 50000
    int n_edges = in_sizes[10];       // 400000
    int nw1 = in_sizes[3];            // 200*512
    int nw2 = in_sizes[6];            // 200*1024

    char* ws = (char*)d_ws;
    float* h1b    = (float*)ws;                       ws += (size_t)n_nodes * 64 * 4;
    float* h2b    = (float*)ws;                       ws += (size_t)n_nodes * 128 * 4;
    unsigned short* h1h = (unsigned short*)ws;        ws += (size_t)n_nodes * 64 * 2;
    unsigned short* w1h = (unsigned short*)ws;        ws += (size_t)nw1 * 2;
    unsigned short* w2h = (unsigned short*)ws;        ws += (size_t)nw2 * 2;
    unsigned* pkA = (unsigned*)ws;                    ws += (size_t)n_edges * 4;
    unsigned* pkB = (unsigned*)ws;                    ws += (size_t)n_edges * 4;
    float* norm_s = (float*)ws;                       ws += (size_t)n_edges * 4;
    int*   deg    = (int*)ws;                         ws += (size_t)n_nodes * 4;
    int*   fil    = (int*)ws;                         ws += (size_t)n_nodes * 4;
    int*   off    = (int*)ws;                         ws += (size_t)(n_nodes + 1) * 4;
    int*   bsum   = (int*)ws;

    int blk = 256;
    int nb = (n_nodes + 255) / 256;
    int nt = (n_nodes + 15) / 16;     // 3125 row tiles
    // CSR build + weight conversion
    hipMemsetAsync(deg, 0, (size_t)n_nodes * 8, stream);
    cvt_w<<<(nw1 + nw2 + blk - 1) / blk, blk, 0, stream>>>(w1, w2, w1h, w2h, nw1, nw2);
    hist<<<(n_edges + blk - 1) / blk, blk, 0, stream>>>(dst, deg, n_edges);
    scan_part<<<nb, 256, 0, stream>>>(deg, bsum, n_nodes);
    scan_bsum<<<1, 256, 0, stream>>>(bsum, off, nb, n_nodes);
    scan_write<<<nb, 256, 0, stream>>>(deg, bsum, off, n_nodes);
    scatter_pack<<<(n_edges + blk - 1) / blk, blk, 0, stream>>>(src, dst, rel, norm, h_ids, off, fil, pkA, pkB, norm_s, n_edges);
    // layer 1
    gemm1_mfma<<<nt, blk, 0, stream>>>(emb, h_ids, lw1, b1, h1b, n_nodes);
    edge1<<<4096, blk, 0, stream>>>(emb, w1h, h1b, off, pkA, norm_s, h1h, n_nodes);
    // layer 2
    gemm2_mfma<<<nt, blk, 0, stream>>>(h1h, lw2, b2, h2b, n_nodes);
    edge2<<<4096, blk, 0, stream>>>(h1h, w2h, h2b, eps, off, pkB, norm_s, out, n_nodes);
}